// Round 5
// baseline (572.476 us; speedup 1.0000x reference)
//
#include <hip/hip_runtime.h>
#include <hip/hip_bf16.h>
#include <cstdint>

#define BB 128
#define LL 256
#define DD 300
#define HH 512
#define TOUT 511
#define NGATE 2560   // 5*H

typedef __attribute__((ext_vector_type(8))) short bf16x8;
typedef __attribute__((ext_vector_type(4))) float f32x4;

__device__ __forceinline__ float sigf(float x){ return 1.0f/(1.0f+__expf(-x)); }
__device__ __forceinline__ float tanh_fast(float x){ return 1.0f - 2.0f/(__expf(2.0f*x)+1.0f); }

__device__ __forceinline__ void load_lds16(const void* g, void* l) {
  __builtin_amdgcn_global_load_lds(
      (const __attribute__((address_space(1))) unsigned int*)g,
      (__attribute__((address_space(3))) unsigned int*)l, 16, 0, 0);
}

#define VMWAIT(n) asm volatile("s_waitcnt vmcnt(" #n ")" ::: "memory")

// ---- transpose+convert: src f32 [Ksrc][2560] -> dst bf16 [2560][Kdst]
__global__ __launch_bounds__(256) void transpose_cvt(const float* __restrict__ src,
    __hip_bfloat16* __restrict__ dst, int Ksrc, int Kdst, int koff)
{
  __shared__ float t[64][65];
  const int tid = threadIdx.x;
  const int k0 = blockIdx.x * 64;
  const int n0 = blockIdx.y * 64;
  #pragma unroll
  for (int p = 0; p < 16; ++p) {
    int lin = p*256 + tid;
    int ki = lin >> 6, nj = lin & 63;
    t[ki][nj] = (k0 + ki < Ksrc) ? src[(size_t)(k0+ki)*NGATE + n0 + nj] : 0.f;
  }
  __syncthreads();
  #pragma unroll
  for (int p = 0; p < 16; ++p) {
    int lin = p*256 + tid;
    int ni = lin >> 6, kj = lin & 63;
    dst[(size_t)(n0+ni)*Kdst + koff + k0 + kj] = __float2bfloat16(t[kj][ni]);
  }
}

// ---- embedding gather + cvt: A0 bf16 [32768][320]
__global__ void embed_cvt(const int* __restrict__ tok, const float* __restrict__ emb,
                          __hip_bfloat16* __restrict__ A0)
{
  int k = blockIdx.x * 64 + threadIdx.x;
  int r = blockIdx.y * 4 + threadIdx.y;
  int tk = tok[r];
  float v = (k < DD) ? emb[(size_t)tk*DD + k] : 0.f;
  A0[(size_t)r*320 + k] = __float2bfloat16(v);
}

// ---- fused GEMM + tree-LSTM cell, phase-split schedule (T3+T4):
// BK=32, 4 LDS buffers, 2-tile prefetch, counted vmcnt at tile top (never 0
// in steady state), 2 MFMA phases per tile with per-phase barriers + setprio.
// A bf16 [M][K], Wt bf16 [2560][K]. Block: BM rows x 64 h-cols (320 gate cols).
// 8 waves: 2(m, WM rows) x 4(n, 16 h-cols gate-aligned). n-strip = bid&7 (T1).
template<int BM>
__global__ __launch_bounds__(512, 2) void gemm_cell(
    const __hip_bfloat16* __restrict__ A, const __hip_bfloat16* __restrict__ Wt,
    int K, const float* __restrict__ bias, const float* __restrict__ cprev,
    float* __restrict__ out, __hip_bfloat16* __restrict__ hout, float* __restrict__ cout,
    int lkshift, int sc)
{
  constexpr int WM   = BM/2;
  constexpr int MFR  = WM/16;          // 8 (BM=256) or 4 (BM=128)
  constexpr int HMF  = MFR/2;
  constexpr int ABYT = BM*64;          // A: BM x 32 bf16
  constexpr int BUFS = ABYT + 20480;   // + B: 320 x 32 bf16
  constexpr int AISS = ABYT/1024;      // 16 or 8
  constexpr int TISS = AISS + 20;      // 36 or 28
  constexpr int NH   = (TISS + 7)/8;   // 5 or 4 (waves 0-3)
  constexpr int NL   = (TISS - 4*NH)/4;// 4 or 3 (waves 4-7)
  __shared__ __align__(16) char lds[4*BUFS];

  const int tid  = threadIdx.x;
  const int lane = tid & 63;
  const int wid  = tid >> 6;
  const int wm   = wid >> 2;
  const int wn   = wid & 3;
  const int bid  = blockIdx.x;
  const int r0   = (bid >> 3) * BM;
  const int n0   = (bid & 7) * 64;
  const int ibase = (wid < 4) ? wid*NH : 4*NH + (wid-4)*NL;
  const int icnt  = (wid < 4) ? NH : NL;
  const int ih    = (icnt + 1) >> 1;
  const size_t rowK = (size_t)K * 2;

  // stage issues [lo,hi) of tile kt into buf kt&3.
  // LDS rows are 64B (32 k-elems); swizzle: chunk ^= (row>>1)&3 (2-way max).
  // Linear LDS dest (base + lane*16) + pre-swizzled global source (rule 21).
  auto stage = [&](int kt, int lo, int hi){
    char* base = lds + (size_t)(kt & 3)*BUFS;
    const int kb = kt*64;
    for (int ii = lo; ii < hi; ++ii) {
      int gi = ibase + ii;
      int rl = gi*16 + (lane >> 2);
      int cg = (lane & 3) ^ ((rl >> 1) & 3);
      const char* g;
      if (gi < AISS) {
        g = (const char*)A + (size_t)(r0 + rl)*rowK + kb + cg*16;
      } else {
        int c = rl - BM;
        int row = (c >> 6)*512 + n0 + (c & 63);
        g = (const char*)Wt + (size_t)row*rowK + kb + cg*16;
      }
      load_lds16(g, base + gi*1024);
    }
  };

  f32x4 acc[MFR][5];
  #pragma unroll
  for (int mf = 0; mf < MFR; ++mf)
    #pragma unroll
    for (int g5 = 0; g5 < 5; ++g5)
      acc[mf][g5] = (f32x4){0.f,0.f,0.f,0.f};

  const int nk = K >> 5;
  stage(0, 0, icnt);
  stage(1, 0, icnt);

  for (int kt = 0; kt < nk; ++kt) {
    // tile top: counted wait (FIFO vmcnt: leaves only tile kt+1's loads in flight)
    if (kt + 1 < nk) {
      if constexpr (BM == 256) { if (wid < 4) VMWAIT(5); else VMWAIT(4); }
      else                     { if (wid < 4) VMWAIT(4); else VMWAIT(3); }
    } else {
      VMWAIT(0);
    }
    __builtin_amdgcn_s_barrier();
    const char* bb = lds + (size_t)(kt & 3)*BUFS;

    // ---- phase 0: b[5] + a[0..HMF) reads, first stage slice, MFMA quadrant 0
    bf16x8 bfr[5];
    #pragma unroll
    for (int g5 = 0; g5 < 5; ++g5) {
      int c = g5*64 + wn*16 + (lane & 15);
      int q = (lane >> 4) ^ ((c >> 1) & 3);
      bfr[g5] = *(const bf16x8*)(bb + ABYT + c*64 + q*16);
    }
    bf16x8 a0[HMF];
    #pragma unroll
    for (int mf = 0; mf < HMF; ++mf) {
      int r = wm*WM + mf*16 + (lane & 15);
      int q = (lane >> 4) ^ ((r >> 1) & 3);
      a0[mf] = *(const bf16x8*)(bb + r*64 + q*16);
    }
    if (kt + 2 < nk) stage(kt + 2, 0, ih);
    __builtin_amdgcn_s_barrier();
    asm volatile("s_waitcnt lgkmcnt(0)" ::: "memory");
    __builtin_amdgcn_sched_barrier(0);
    __builtin_amdgcn_s_setprio(1);
    #pragma unroll
    for (int mf = 0; mf < HMF; ++mf)
      #pragma unroll
      for (int g5 = 0; g5 < 5; ++g5)
        acc[mf][g5] = __builtin_amdgcn_mfma_f32_16x16x32_bf16(a0[mf], bfr[g5], acc[mf][g5], 0, 0, 0);
    __builtin_amdgcn_s_setprio(0);

    // ---- phase 1: a[HMF..MFR) reads, second stage slice, MFMA quadrant 1
    bf16x8 a1[HMF];
    #pragma unroll
    for (int mf = 0; mf < HMF; ++mf) {
      int r = wm*WM + (HMF + mf)*16 + (lane & 15);
      int q = (lane >> 4) ^ ((r >> 1) & 3);
      a1[mf] = *(const bf16x8*)(bb + r*64 + q*16);
    }
    if (kt + 2 < nk) stage(kt + 2, ih, icnt);
    __builtin_amdgcn_s_barrier();
    asm volatile("s_waitcnt lgkmcnt(0)" ::: "memory");
    __builtin_amdgcn_sched_barrier(0);
    __builtin_amdgcn_s_setprio(1);
    #pragma unroll
    for (int mf = 0; mf < HMF; ++mf)
      #pragma unroll
      for (int g5 = 0; g5 < 5; ++g5)
        acc[HMF+mf][g5] = __builtin_amdgcn_mfma_f32_16x16x32_bf16(a1[mf], bfr[g5], acc[HMF+mf][g5], 0, 0, 0);
    __builtin_amdgcn_s_setprio(0);
  }

  // epilogue: fused LSTM cell
  const int Lmask = (1 << lkshift) - 1;
  const int jg = n0 + wn*16 + (lane & 15);
  float bia[5];
  #pragma unroll
  for (int g5 = 0; g5 < 5; ++g5) bia[g5] = bias[g5*HH + jg];
  #pragma unroll
  for (int mf = 0; mf < MFR; ++mf) {
    #pragma unroll
    for (int v = 0; v < 4; ++v) {
      int r = r0 + wm*WM + mf*16 + (lane >> 4)*4 + v;
      float gi  = acc[mf][0][v] + bia[0];
      float gfl = acc[mf][1][v] + bia[1];
      float gfr = acc[mf][2][v] + bia[2];
      float go  = acc[mf][3][v] + bia[3];
      float gu  = acc[mf][4][v] + bia[4];
      float cl = 0.f, cr = 0.f;
      if (cprev) {
        cl = cprev[(size_t)(2*r)*HH + jg];
        cr = cprev[(size_t)(2*r)*HH + HH + jg];
      }
      float cc = sigf(gi)*tanh_fast(gu) + sigf(gfl)*cl + sigf(gfr)*cr;
      float hh = sigf(go)*tanh_fast(cc);
      int b = r >> lkshift;
      int t = r & Lmask;
      out[((size_t)b*TOUT + sc + t)*HH + jg] = hh;
      hout[(size_t)r*HH + jg] = __float2bfloat16(hh);
      cout[(size_t)r*HH + jg] = cc;
    }
  }
}

extern "C" void kernel_launch(void* const* d_in, const int* in_sizes, int n_in,
                              void* d_out, int out_size, void* d_ws, size_t ws_size,
                              hipStream_t stream) {
  (void)in_sizes; (void)n_in; (void)out_size; (void)ws_size;
  const int*   tok  = (const int*)d_in[0];
  const float* emb  = (const float*)d_in[1];
  const float* Wx   = (const float*)d_in[2];
  const float* Ul   = (const float*)d_in[3];
  const float* Ur   = (const float*)d_in[4];
  const float* bias = (const float*)d_in[5];
  float* out = (float*)d_out;

  char* ws = (char*)d_ws;
  size_t off = 0;
  __hip_bfloat16* Wb0t = (__hip_bfloat16*)(ws + off); off += (size_t)NGATE*320*2;
  __hip_bfloat16* Wb1t = (__hip_bfloat16*)(ws + off); off += (size_t)NGATE*1024*2;
  __hip_bfloat16* hA   = (__hip_bfloat16*)(ws + off); off += (size_t)32768*HH*2;
  __hip_bfloat16* hB   = (__hip_bfloat16*)(ws + off); off += (size_t)16384*HH*2;
  float*          cA   = (float*)(ws + off);          off += (size_t)32768*HH*4;
  float*          cB   = (float*)(ws + off);          off += (size_t)16384*HH*4;
  __hip_bfloat16* A0   = (__hip_bfloat16*)cB;   // alias: A0 dead before cB first written

  transpose_cvt<<<dim3(5, 40), 256, 0, stream>>>(Wx, Wb0t, DD, 320, 0);
  transpose_cvt<<<dim3(8, 40), 256, 0, stream>>>(Ul, Wb1t, HH, 1024, 0);
  transpose_cvt<<<dim3(8, 40), 256, 0, stream>>>(Ur, Wb1t, HH, 1024, 512);
  embed_cvt<<<dim3(5, 8192), dim3(64,4), 0, stream>>>(tok, emb, A0);

  // level 0: M=32768, K=320 (nk=10)
  gemm_cell<256><<<(32768/256)*8, 512, 0, stream>>>(A0, Wb0t, 320, bias, nullptr,
                                                    out, hA, cA, 8, 0);
  // levels 1..8: M = 32768>>k, K=1024 (nk=32)
  for (int k = 1; k <= 8; ++k) {
    int M = 32768 >> k;
    int sc = HH - (HH >> k);
    const __hip_bfloat16* Ain = (k & 1) ? hA : hB;
    __hip_bfloat16*       hO  = (k & 1) ? hB : hA;
    const float*          cI  = (k & 1) ? cA : cB;
    float*                cO  = (k & 1) ? cB : cA;
    if (M >= 8192) {
      gemm_cell<256><<<(M/256)*8, 512, 0, stream>>>(Ain, Wb1t, 1024, bias, cI,
                                                    out, hO, cO, 8 - k, sc);
    } else {
      gemm_cell<128><<<(M/128)*8, 512, 0, stream>>>(Ain, Wb1t, 1024, bias, cI,
                                                    out, hO, cO, 8 - k, sc);
    }
  }
}

// Round 6
// 518.271 us; speedup vs baseline: 1.1046x; 1.1046x over previous
//
#include <hip/hip_runtime.h>
#include <hip/hip_bf16.h>
#include <cstdint>

#define BB 128
#define LL 256
#define DD 300
#define HH 512
#define TOUT 511
#define NGATE 2560   // 5*H

typedef __attribute__((ext_vector_type(8))) short bf16x8;
typedef __attribute__((ext_vector_type(4))) float f32x4;

__device__ __forceinline__ float sigf(float x){ return 1.0f/(1.0f+__expf(-x)); }
__device__ __forceinline__ float tanh_fast(float x){ return 1.0f - 2.0f/(__expf(2.0f*x)+1.0f); }

__device__ __forceinline__ void load_lds16(const void* g, void* l) {
  __builtin_amdgcn_global_load_lds(
      (const __attribute__((address_space(1))) unsigned int*)g,
      (__attribute__((address_space(3))) unsigned int*)l, 16, 0, 0);
}

#define VMWAIT(n) asm volatile("s_waitcnt vmcnt(" #n ")" ::: "memory")

// ---- transpose+convert: src f32 [Ksrc][2560] -> dst bf16 [2560][Kdst]
__global__ __launch_bounds__(256) void transpose_cvt(const float* __restrict__ src,
    __hip_bfloat16* __restrict__ dst, int Ksrc, int Kdst, int koff)
{
  __shared__ float t[64][65];
  const int tid = threadIdx.x;
  const int k0 = blockIdx.x * 64;
  const int n0 = blockIdx.y * 64;
  #pragma unroll
  for (int p = 0; p < 16; ++p) {
    int lin = p*256 + tid;
    int ki = lin >> 6, nj = lin & 63;
    t[ki][nj] = (k0 + ki < Ksrc) ? src[(size_t)(k0+ki)*NGATE + n0 + nj] : 0.f;
  }
  __syncthreads();
  #pragma unroll
  for (int p = 0; p < 16; ++p) {
    int lin = p*256 + tid;
    int ni = lin >> 6, kj = lin & 63;
    dst[(size_t)(n0+ni)*Kdst + koff + k0 + kj] = __float2bfloat16(t[kj][ni]);
  }
}

// ---- embedding gather + cvt: A0 bf16 [32768][320]
__global__ void embed_cvt(const int* __restrict__ tok, const float* __restrict__ emb,
                          __hip_bfloat16* __restrict__ A0)
{
  int k = blockIdx.x * 64 + threadIdx.x;
  int r = blockIdx.y * 4 + threadIdx.y;
  int tk = tok[r];
  float v = (k < DD) ? emb[(size_t)tk*DD + k] : 0.f;
  A0[(size_t)r*320 + k] = __float2bfloat16(v);
}

// ---- shared epilogue: gates -> h, c, writes
__device__ __forceinline__ void cell_epilogue(
    const f32x4* accmf /*[5] for one mf*/, int r, int jg,
    const float* bia, const float* __restrict__ cprev,
    float* __restrict__ out, __hip_bfloat16* __restrict__ hout,
    float* __restrict__ cout, int lkshift, int sc, int lane)
{
  const int Lmask = (1 << lkshift) - 1;
  #pragma unroll
  for (int v = 0; v < 4; ++v) {
    int rr = r + (lane >> 4)*4 + v;
    float gi  = accmf[0][v] + bia[0];
    float gfl = accmf[1][v] + bia[1];
    float gfr = accmf[2][v] + bia[2];
    float go  = accmf[3][v] + bia[3];
    float gu  = accmf[4][v] + bia[4];
    float cl = 0.f, cr = 0.f;
    if (cprev) {
      cl = cprev[(size_t)(2*rr)*HH + jg];
      cr = cprev[(size_t)(2*rr)*HH + HH + jg];
    }
    float cc = sigf(gi)*tanh_fast(gu) + sigf(gfl)*cl + sigf(gfr)*cr;
    float hh = sigf(go)*tanh_fast(cc);
    int b = rr >> lkshift;
    int t = rr & Lmask;
    out[((size_t)b*TOUT + sc + t)*HH + jg] = hh;
    hout[(size_t)rr*HH + jg] = __float2bfloat16(hh);
    cout[(size_t)rr*HH + jg] = cc;
  }
}

// ================= V_A: BM=128, BK=32, 56KB LDS -> 2 blocks/CU (occupancy) ====
// 512 thr, 8 waves 2(m)x4(n). Staging: 28 x 1KB issues; wid0-1:A(4), wid2-3:B(4),
// wid4-7:B(3). Pointers hoisted; loop advances kb += 64B. Simple R4-sync.
__global__ __launch_bounds__(512, 4) void gemm_cellA(
    const __hip_bfloat16* __restrict__ A, const __hip_bfloat16* __restrict__ Wt,
    int K, const float* __restrict__ bias, const float* __restrict__ cprev,
    float* __restrict__ out, __hip_bfloat16* __restrict__ hout, float* __restrict__ cout,
    int lkshift, int sc)
{
  constexpr int BUFS = 28672;       // A 128x32 bf16 (8KB) + B 320x32 bf16 (20KB)
  __shared__ __align__(16) char lds[2*BUFS];

  const int tid  = threadIdx.x;
  const int lane = tid & 63;
  const int wid  = tid >> 6;
  const int wm   = wid >> 2;        // 0..1 (64-row half)
  const int wn   = wid & 3;         // 0..3 (16 h-col strip)
  const int bid  = blockIdx.x;
  const int r0   = (bid >> 3) * 128;
  const int n0   = (bid & 7) * 64;
  const size_t rowK = (size_t)K * 2;

  // hoisted staging pointers (per-thread), advanced by 64B per K-tile
  const int niss = (wid < 4) ? 4 : 3;
  const char* gsrc[4];
  int gi0 = (wid < 4) ? wid*4 : 16 + (wid-4)*3;
  #pragma unroll
  for (int i = 0; i < 4; ++i) {
    int gi = gi0 + i;
    int row = (gi < 8) ? gi*16 + (lane >> 2) : (gi-8)*16 + (lane >> 2);
    int cg = (lane & 3) ^ ((row >> 1) & 3);
    if (gi < 8) {
      gsrc[i] = (const char*)A + (size_t)(r0 + row)*rowK + cg*16;
    } else {
      int grow = (row >> 6)*512 + n0 + (row & 63);
      gsrc[i] = (const char*)Wt + (size_t)grow*rowK + cg*16;
    }
  }
  const int ldst0 = gi0*1024 + lane*16;

  f32x4 acc[4][5];
  #pragma unroll
  for (int mf = 0; mf < 4; ++mf)
    #pragma unroll
    for (int g5 = 0; g5 < 5; ++g5)
      acc[mf][g5] = (f32x4){0.f,0.f,0.f,0.f};

  const int nk = K >> 5;
  auto stage = [&](int buf, int kt){
    char* base = lds + buf*BUFS + ldst0;
    const size_t kb = (size_t)kt*64;
    if (wid < 4) {
      #pragma unroll
      for (int i = 0; i < 4; ++i) load_lds16(gsrc[i] + kb, base + i*1024);
    } else {
      #pragma unroll
      for (int i = 0; i < 3; ++i) load_lds16(gsrc[i] + kb, base + i*1024);
    }
  };

  stage(0, 0);
  int cur = 0;
  for (int kt = 0; kt < nk; ++kt) {
    if (kt + 1 < nk) {
      stage(cur ^ 1, kt + 1);
      if (wid < 4) VMWAIT(4); else VMWAIT(3);
    } else {
      VMWAIT(0);
    }
    __builtin_amdgcn_s_barrier();

    const char* Ab = lds + cur*BUFS;
    const char* Bb = Ab + 8192;
    const int q = lane >> 4;
    bf16x8 b[5];
    #pragma unroll
    for (int g5 = 0; g5 < 5; ++g5) {
      int c = g5*64 + wn*16 + (lane & 15);
      b[g5] = *(const bf16x8*)(Bb + c*64 + ((q ^ ((c >> 1) & 3))*16));
    }
    __builtin_amdgcn_s_setprio(1);
    #pragma unroll
    for (int mf = 0; mf < 4; ++mf) {
      int r = wm*64 + mf*16 + (lane & 15);
      bf16x8 av = *(const bf16x8*)(Ab + r*64 + ((q ^ ((r >> 1) & 3))*16));
      #pragma unroll
      for (int g5 = 0; g5 < 5; ++g5)
        acc[mf][g5] = __builtin_amdgcn_mfma_f32_16x16x32_bf16(av, b[g5], acc[mf][g5], 0, 0, 0);
    }
    __builtin_amdgcn_s_setprio(0);
    __builtin_amdgcn_s_barrier();
    cur ^= 1;
  }

  const int jg = n0 + wn*16 + (lane & 15);
  float bia[5];
  #pragma unroll
  for (int g5 = 0; g5 < 5; ++g5) bia[g5] = bias[g5*HH + jg];
  #pragma unroll
  for (int mf = 0; mf < 4; ++mf)
    cell_epilogue(acc[mf], r0 + wm*64 + mf*16, jg, bia, cprev,
                  out, hout, cout, lkshift, sc, lane);
}

// ================= V_B: R4 control (BM=256/128, BK=64, 1 block/CU) ===========
template<int WM>
__global__ __launch_bounds__(512, 2) void gemm_cellB(
    const __hip_bfloat16* __restrict__ A, const __hip_bfloat16* __restrict__ Wt,
    int K, const float* __restrict__ bias, const float* __restrict__ cprev,
    float* __restrict__ out, __hip_bfloat16* __restrict__ hout, float* __restrict__ cout,
    int lkshift, int sc)
{
  constexpr int BM     = 2*WM;
  constexpr int ABYTES = BM*128;
  constexpr int BUFS   = ABYTES + 40960;
  constexpr int AISS   = BM/8;
  constexpr int NISS   = (AISS + 40)/8;
  constexpr int MFR    = WM/16;
  __shared__ __align__(16) char lds[2*BUFS];

  const int tid  = threadIdx.x;
  const int lane = tid & 63;
  const int wid  = tid >> 6;
  const int wm   = wid >> 2;
  const int wn   = wid & 3;
  const int bid  = blockIdx.x;
  const int r0   = (bid >> 3) * BM;
  const int n0   = (bid & 7) * 64;

  f32x4 acc[MFR][5];
  #pragma unroll
  for (int mf = 0; mf < MFR; ++mf)
    #pragma unroll
    for (int g5 = 0; g5 < 5; ++g5)
      acc[mf][g5] = (f32x4){0.f,0.f,0.f,0.f};

  const int srow = lane >> 3;
  const int gq   = (lane & 7) ^ srow;
  const int nk = K >> 6;

  auto stage = [&](int buf, int kt){
    const int k0 = kt << 6;
    char* base = lds + buf*BUFS;
    #pragma unroll
    for (int ii = 0; ii < NISS; ++ii) {
      int issue = wid*NISS + ii;
      if (issue < AISS) {
        int r = issue*8 + srow;
        const char* g = (const char*)A + ((size_t)(r0 + r)*K + k0)*2 + (size_t)gq*16;
        load_lds16(g, base + issue*1024);
      } else {
        int c = (issue-AISS)*8 + srow;
        int gg = c >> 6, j = c & 63;
        const char* g = (const char*)Wt + ((size_t)(gg*512 + n0 + j)*K + k0)*2 + (size_t)gq*16;
        load_lds16(g, base + ABYTES + (issue-AISS)*1024);
      }
    }
  };

  stage(0, 0);
  int cur = 0;
  for (int kt = 0; kt < nk; ++kt) {
    if (kt + 1 < nk) {
      stage(cur ^ 1, kt + 1);
      if constexpr (NISS == 9) VMWAIT(9); else VMWAIT(7);
    } else {
      VMWAIT(0);
    }
    __builtin_amdgcn_s_barrier();

    const char* Ab = lds + cur*BUFS;
    const char* Bb = Ab + ABYTES;
    __builtin_amdgcn_s_setprio(1);
    #pragma unroll
    for (int s = 0; s < 2; ++s) {
      const int qb = s*4 + (lane >> 4);
      bf16x8 b[5];
      #pragma unroll
      for (int g5 = 0; g5 < 5; ++g5) {
        int c = g5*64 + wn*16 + (lane & 15);
        b[g5] = *(const bf16x8*)(Bb + c*128 + ((qb ^ (c & 7))*16));
      }
      #pragma unroll
      for (int mf = 0; mf < MFR; ++mf) {
        int r = wm*WM + mf*16 + (lane & 15);
        bf16x8 av = *(const bf16x8*)(Ab + r*128 + ((qb ^ (r & 7))*16));
        #pragma unroll
        for (int g5 = 0; g5 < 5; ++g5)
          acc[mf][g5] = __builtin_amdgcn_mfma_f32_16x16x32_bf16(av, b[g5], acc[mf][g5], 0, 0, 0);
      }
    }
    __builtin_amdgcn_s_setprio(0);
    __builtin_amdgcn_s_barrier();
    cur ^= 1;
  }

  const int jg = n0 + wn*16 + (lane & 15);
  float bia[5];
  #pragma unroll
  for (int g5 = 0; g5 < 5; ++g5) bia[g5] = bias[g5*HH + jg];
  #pragma unroll
  for (int mf = 0; mf < MFR; ++mf)
    cell_epilogue(acc[mf], r0 + wm*WM + mf*16, jg, bia, cprev,
                  out, hout, cout, lkshift, sc, lane);
}

extern "C" void kernel_launch(void* const* d_in, const int* in_sizes, int n_in,
                              void* d_out, int out_size, void* d_ws, size_t ws_size,
                              hipStream_t stream) {
  (void)in_sizes; (void)n_in; (void)out_size; (void)ws_size;
  const int*   tok  = (const int*)d_in[0];
  const float* emb  = (const float*)d_in[1];
  const float* Wx   = (const float*)d_in[2];
  const float* Ul   = (const float*)d_in[3];
  const float* Ur   = (const float*)d_in[4];
  const float* bias = (const float*)d_in[5];
  float* out = (float*)d_out;

  char* ws = (char*)d_ws;
  size_t off = 0;
  __hip_bfloat16* Wb0t = (__hip_bfloat16*)(ws + off); off += (size_t)NGATE*320*2;
  __hip_bfloat16* Wb1t = (__hip_bfloat16*)(ws + off); off += (size_t)NGATE*1024*2;
  __hip_bfloat16* hA   = (__hip_bfloat16*)(ws + off); off += (size_t)32768*HH*2;
  __hip_bfloat16* hB   = (__hip_bfloat16*)(ws + off); off += (size_t)16384*HH*2;
  float*          cA   = (float*)(ws + off);          off += (size_t)32768*HH*4;
  float*          cB   = (float*)(ws + off);          off += (size_t)16384*HH*4;
  __hip_bfloat16* A0   = (__hip_bfloat16*)cB;

  transpose_cvt<<<dim3(5, 40), 256, 0, stream>>>(Wx, Wb0t, DD, 320, 0);
  transpose_cvt<<<dim3(8, 40), 256, 0, stream>>>(Ul, Wb1t, HH, 1024, 0);
  transpose_cvt<<<dim3(8, 40), 256, 0, stream>>>(Ur, Wb1t, HH, 1024, 512);
  embed_cvt<<<dim3(5, 8192), dim3(64,4), 0, stream>>>(tok, emb, A0);

  // level 0 (V_A): M=32768, K=320
  gemm_cellA<<<(32768/128)*8, 512, 0, stream>>>(A0, Wb0t, 320, bias, nullptr,
                                                out, hA, cA, 8, 0);
  // levels 1..8: V_A on even levels, V_B (R4 control) on odd levels
  for (int k = 1; k <= 8; ++k) {
    int M = 32768 >> k;
    int sc = HH - (HH >> k);
    const __hip_bfloat16* Ain = (k & 1) ? hA : hB;
    __hip_bfloat16*       hO  = (k & 1) ? hB : hA;
    const float*          cI  = (k & 1) ? cA : cB;
    float*                cO  = (k & 1) ? cB : cA;
    if (k & 1) {
      if (M >= 8192)
        gemm_cellB<128><<<(M/256)*8, 512, 0, stream>>>(Ain, Wb1t, 1024, bias, cI,
                                                       out, hO, cO, 8 - k, sc);
      else
        gemm_cellB<64><<<(M/128)*8, 512, 0, stream>>>(Ain, Wb1t, 1024, bias, cI,
                                                      out, hO, cO, 8 - k, sc);
    } else {
      gemm_cellA<<<(M/128)*8, 512, 0, stream>>>(Ain, Wb1t, 1024, bias, cI,
                                                out, hO, cO, 8 - k, sc);
    }
  }
}

// Round 7
// 468.385 us; speedup vs baseline: 1.2222x; 1.1065x over previous
//
#include <hip/hip_runtime.h>
#include <hip/hip_bf16.h>
#include <cstdint>

#define BB 128
#define LL 256
#define DD 300
#define HH 512
#define TOUT 511
#define NGATE 2560   // 5*H

typedef __attribute__((ext_vector_type(8))) short bf16x8;
typedef __attribute__((ext_vector_type(4))) float f32x4;

// fast transcendentals: v_rcp_f32 + v_exp_f32 (exp2)
__device__ __forceinline__ float rcpf(float x){ return __builtin_amdgcn_rcpf(x); }
__device__ __forceinline__ float ex2f(float x){ return __builtin_amdgcn_exp2f(x); }
__device__ __forceinline__ float sigf(float x){ return rcpf(1.0f + ex2f(x * -1.44269504f)); }
__device__ __forceinline__ float tanh_fast(float x){ return 1.0f - 2.0f*rcpf(ex2f(x * 2.88539008f) + 1.0f); }

__device__ __forceinline__ void load_lds16(const void* g, void* l) {
  __builtin_amdgcn_global_load_lds(
      (const __attribute__((address_space(1))) unsigned int*)g,
      (__attribute__((address_space(3))) unsigned int*)l, 16, 0, 0);
}

#define VMWAIT(n) asm volatile("s_waitcnt vmcnt(" #n ")" ::: "memory")

// ---- transpose+convert: src f32 [Ksrc][2560] -> dst bf16 [2560][Kdst]
__global__ __launch_bounds__(256) void transpose_cvt(const float* __restrict__ src,
    __hip_bfloat16* __restrict__ dst, int Ksrc, int Kdst, int koff)
{
  __shared__ float t[64][65];
  const int tid = threadIdx.x;
  const int k0 = blockIdx.x * 64;
  const int n0 = blockIdx.y * 64;
  #pragma unroll
  for (int p = 0; p < 16; ++p) {
    int lin = p*256 + tid;
    int ki = lin >> 6, nj = lin & 63;
    t[ki][nj] = (k0 + ki < Ksrc) ? src[(size_t)(k0+ki)*NGATE + n0 + nj] : 0.f;
  }
  __syncthreads();
  #pragma unroll
  for (int p = 0; p < 16; ++p) {
    int lin = p*256 + tid;
    int ni = lin >> 6, kj = lin & 63;
    dst[(size_t)(n0+ni)*Kdst + koff + k0 + kj] = __float2bfloat16(t[kj][ni]);
  }
}

// ---- embedding gather + cvt: A0 bf16 [32768][320]
__global__ void embed_cvt(const int* __restrict__ tok, const float* __restrict__ emb,
                          __hip_bfloat16* __restrict__ A0)
{
  int k = blockIdx.x * 64 + threadIdx.x;
  int r = blockIdx.y * 4 + threadIdx.y;
  int tk = tok[r];
  float v = (k < DD) ? emb[(size_t)tk*DD + k] : 0.f;
  A0[(size_t)r*320 + k] = __float2bfloat16(v);
}

// ---- fused GEMM + tree-LSTM cell (V_A structure: BM=128, BK=32, 2 blocks/CU)
// A bf16 [M][K], Wt bf16 [2560][K]. Block: 128 rows x 64 h-cols (320 gate cols).
// 8 waves 2(m)x4(n, gate-aligned). XCD co-location: panel p's 8 strip-blocks
// have bid === p (mod 8) -> same XCD, temporally adjacent (A stays L2-hot).
__global__ __launch_bounds__(512, 4) void gemm_cell(
    const __hip_bfloat16* __restrict__ A, const __hip_bfloat16* __restrict__ Wt,
    int K, const float* __restrict__ bias, const float* __restrict__ cprev,
    float* __restrict__ out, __hip_bfloat16* __restrict__ hout, float* __restrict__ cout,
    int lkshift, int sc, int numM)
{
  constexpr int BUFS = 28672;       // A 128x32 bf16 (8KB) + B 320x32 bf16 (20KB)
  __shared__ __align__(16) char lds[2*BUFS];

  const int tid  = threadIdx.x;
  const int lane = tid & 63;
  const int wid  = tid >> 6;
  const int wm   = wid >> 2;        // 0..1 (64-row half)
  const int wn   = wid & 3;         // 0..3 (16 h-col strip)
  const int bid  = blockIdx.x;
  int m, s;
  if (numM >= 8) { m = (bid & 7) + ((bid >> 6) << 3); s = (bid >> 3) & 7; }
  else           { m = bid % numM;  s = bid / numM; }
  const int r0   = m * 128;
  const int n0   = s * 64;
  const size_t rowK = (size_t)K * 2;

  // hoisted staging pointers (per-thread), advanced by 64B per K-tile
  const char* gsrc[4];
  int gi0 = (wid < 4) ? wid*4 : 16 + (wid-4)*3;
  #pragma unroll
  for (int i = 0; i < 4; ++i) {
    int gi = gi0 + i;
    int row = (gi < 8) ? gi*16 + (lane >> 2) : (gi-8)*16 + (lane >> 2);
    int cg = (lane & 3) ^ ((row >> 1) & 3);
    if (gi < 8) {
      gsrc[i] = (const char*)A + (size_t)(r0 + row)*rowK + cg*16;
    } else {
      int grow = (row >> 6)*512 + n0 + (row & 63);
      gsrc[i] = (const char*)Wt + (size_t)grow*rowK + cg*16;
    }
  }
  const int ldst0 = gi0*1024 + lane*16;

  f32x4 acc[4][5];
  #pragma unroll
  for (int mf = 0; mf < 4; ++mf)
    #pragma unroll
    for (int g5 = 0; g5 < 5; ++g5)
      acc[mf][g5] = (f32x4){0.f,0.f,0.f,0.f};

  const int nk = K >> 5;
  auto stage = [&](int buf, int kt){
    char* base = lds + buf*BUFS + ldst0;
    const size_t kb = (size_t)kt*64;
    if (wid < 4) {
      #pragma unroll
      for (int i = 0; i < 4; ++i) load_lds16(gsrc[i] + kb, base + i*1024);
    } else {
      #pragma unroll
      for (int i = 0; i < 3; ++i) load_lds16(gsrc[i] + kb, base + i*1024);
    }
  };

  stage(0, 0);
  int cur = 0;
  for (int kt = 0; kt < nk; ++kt) {
    if (kt + 1 < nk) {
      stage(cur ^ 1, kt + 1);
      if (wid < 4) VMWAIT(4); else VMWAIT(3);
    } else {
      VMWAIT(0);
    }
    __builtin_amdgcn_s_barrier();

    const char* Ab = lds + cur*BUFS;
    const char* Bb = Ab + 8192;
    const int q = lane >> 4;
    bf16x8 b[5];
    #pragma unroll
    for (int g5 = 0; g5 < 5; ++g5) {
      int c = g5*64 + wn*16 + (lane & 15);
      b[g5] = *(const bf16x8*)(Bb + c*64 + ((q ^ ((c >> 1) & 3))*16));
    }
    __builtin_amdgcn_s_setprio(1);
    #pragma unroll
    for (int mf = 0; mf < 4; ++mf) {
      int r = wm*64 + mf*16 + (lane & 15);
      bf16x8 av = *(const bf16x8*)(Ab + r*64 + ((q ^ ((r >> 1) & 3))*16));
      #pragma unroll
      for (int g5 = 0; g5 < 5; ++g5)
        acc[mf][g5] = __builtin_amdgcn_mfma_f32_16x16x32_bf16(av, b[g5], acc[mf][g5], 0, 0, 0);
    }
    __builtin_amdgcn_s_setprio(0);
    __builtin_amdgcn_s_barrier();
    cur ^= 1;
  }

  // epilogue: fused LSTM cell (fast rcp/exp2 forms)
  const int Lmask = (1 << lkshift) - 1;
  const int jg = n0 + wn*16 + (lane & 15);
  float bia[5];
  #pragma unroll
  for (int g5 = 0; g5 < 5; ++g5) bia[g5] = bias[g5*HH + jg];
  #pragma unroll
  for (int mf = 0; mf < 4; ++mf) {
    #pragma unroll
    for (int v = 0; v < 4; ++v) {
      int rr = r0 + wm*64 + mf*16 + (lane >> 4)*4 + v;
      float gi  = acc[mf][0][v] + bia[0];
      float gfl = acc[mf][1][v] + bia[1];
      float gfr = acc[mf][2][v] + bia[2];
      float go  = acc[mf][3][v] + bia[3];
      float gu  = acc[mf][4][v] + bia[4];
      float cl = 0.f, cr = 0.f;
      if (cprev) {
        cl = cprev[(size_t)(2*rr)*HH + jg];
        cr = cprev[(size_t)(2*rr)*HH + HH + jg];
      }
      float cc = sigf(gi)*tanh_fast(gu) + sigf(gfl)*cl + sigf(gfr)*cr;
      float hh = sigf(go)*tanh_fast(cc);
      int b = rr >> lkshift;
      int t = rr & Lmask;
      out[((size_t)b*TOUT + sc + t)*HH + jg] = hh;
      hout[(size_t)rr*HH + jg] = __float2bfloat16(hh);
      cout[(size_t)rr*HH + jg] = cc;
    }
  }
}

extern "C" void kernel_launch(void* const* d_in, const int* in_sizes, int n_in,
                              void* d_out, int out_size, void* d_ws, size_t ws_size,
                              hipStream_t stream) {
  (void)in_sizes; (void)n_in; (void)out_size; (void)ws_size;
  const int*   tok  = (const int*)d_in[0];
  const float* emb  = (const float*)d_in[1];
  const float* Wx   = (const float*)d_in[2];
  const float* Ul   = (const float*)d_in[3];
  const float* Ur   = (const float*)d_in[4];
  const float* bias = (const float*)d_in[5];
  float* out = (float*)d_out;

  char* ws = (char*)d_ws;
  size_t off = 0;
  __hip_bfloat16* Wb0t = (__hip_bfloat16*)(ws + off); off += (size_t)NGATE*320*2;
  __hip_bfloat16* Wb1t = (__hip_bfloat16*)(ws + off); off += (size_t)NGATE*1024*2;
  __hip_bfloat16* hA   = (__hip_bfloat16*)(ws + off); off += (size_t)32768*HH*2;
  __hip_bfloat16* hB   = (__hip_bfloat16*)(ws + off); off += (size_t)16384*HH*2;
  float*          cA   = (float*)(ws + off);          off += (size_t)32768*HH*4;
  float*          cB   = (float*)(ws + off);          off += (size_t)16384*HH*4;
  __hip_bfloat16* A0   = (__hip_bfloat16*)cB;   // alias: A0 dead before cB first written

  transpose_cvt<<<dim3(5, 40), 256, 0, stream>>>(Wx, Wb0t, DD, 320, 0);
  transpose_cvt<<<dim3(8, 40), 256, 0, stream>>>(Ul, Wb1t, HH, 1024, 0);
  transpose_cvt<<<dim3(8, 40), 256, 0, stream>>>(Ur, Wb1t, HH, 1024, 512);
  embed_cvt<<<dim3(5, 8192), dim3(64,4), 0, stream>>>(tok, emb, A0);

  // level 0: M=32768, K=320
  gemm_cell<<<(32768/128)*8, 512, 0, stream>>>(A0, Wb0t, 320, bias, nullptr,
                                               out, hA, cA, 8, 0, 32768/128);
  // levels 1..8: M = 32768>>k, K=1024
  for (int k = 1; k <= 8; ++k) {
    int M = 32768 >> k;
    int sc = HH - (HH >> k);
    const __hip_bfloat16* Ain = (k & 1) ? hA : hB;
    __hip_bfloat16*       hO  = (k & 1) ? hB : hA;
    const float*          cI  = (k & 1) ? cA : cB;
    float*                cO  = (k & 1) ? cB : cA;
    int numM = M / 128;
    gemm_cell<<<numM*8, 512, 0, stream>>>(Ain, Wb1t, 1024, bias, cI,
                                          out, hO, cO, 8 - k, sc, numM);
  }
}